// Round 5
// baseline (197.285 us; speedup 1.0000x reference)
//
#include <hip/hip_runtime.h>
#include <hip/hip_bf16.h>

#define B 4
#define T 4096
#define D 512
#define KKEEP 1024
#define RSQRT_D 0.044194173824159216f  // 1/sqrt(512)

// Monotone float->uint map: preserves total order.
__device__ __forceinline__ unsigned f2ord(float f) {
    unsigned u = __float_as_uint(f);
    return (u & 0x80000000u) ? ~u : (u | 0x80000000u);
}
__device__ __forceinline__ float ord2f(unsigned o) {
    return __uint_as_float((o & 0x80000000u) ? (o ^ 0x80000000u) : ~o);
}

// ---------------------------------------------------------------------------
// Kernel A: per batch — q = h[b,T-1,:]@Wq + bq;  wvec = (Wk@q)*rsqrtD;
// cvec = (bk.q)*rsqrtD.  One 1024-thread block per batch; phases split by LDS.
__global__ __launch_bounds__(1024) void k_prep(const float* __restrict__ h,
                                               const float* __restrict__ Wq,
                                               const float* __restrict__ bq,
                                               const float* __restrict__ Wk,
                                               const float* __restrict__ bk,
                                               float* __restrict__ wvec,
                                               float* __restrict__ cvec) {
    int b = blockIdx.x, tid = threadIdx.x;
    int j = tid & 511, half = tid >> 9;
    int d0 = half * 256;
    __shared__ float hs[D], q[D], partial[1024];
    const float* hrow = h + ((size_t)b * T + (T - 1)) * D;
    if (tid < D) hs[tid] = hrow[tid];
    __syncthreads();
    // q[j] = sum_d hs[d] * Wq[d,j]  (column-coalesced; two d-halves per j)
    float acc = 0.f;
#pragma unroll 4
    for (int d = 0; d < 256; ++d) acc += hs[d0 + d] * Wq[(size_t)(d0 + d) * D + j];
    partial[tid] = acc;
    __syncthreads();
    if (tid < D) q[tid] = partial[tid] + partial[tid + 512] + bq[tid];
    __syncthreads();
    // wvec[j] = sum_k Wk[j,k] * q[k]  (row walk, L1 line reuse across k)
    float acc2 = 0.f;
#pragma unroll 4
    for (int k = 0; k < 256; ++k) acc2 += Wk[(size_t)j * D + d0 + k] * q[d0 + k];
    partial[tid] = acc2;
    __syncthreads();
    if (tid < D) wvec[b * D + tid] = (partial[tid] + partial[tid + 512]) * RSQRT_D;
    if (tid < 64) {
        float a = 0.f;
        for (int k = tid; k < D; k += 64) a += bk[k] * q[k];
        for (int off = 32; off; off >>= 1) a += __shfl_down(a, off);
        if (tid == 0) cvec[b] = a * RSQRT_D;
    }
}

// ---------------------------------------------------------------------------
// Kernel B: sc[b,s] = h[b,s,:] . wvec[b] + cvec[b]   (scaling pre-folded)
__global__ void k_scores(const float* __restrict__ h, const float* __restrict__ wvec,
                         const float* __restrict__ cvec, float* __restrict__ sc) {
    int b = blockIdx.x;
    __shared__ float ws[D];
    for (int i = threadIdx.x; i < D; i += blockDim.x) ws[i] = wvec[b * D + i];
    __syncthreads();
    int lane = threadIdx.x & 63;
    int wave = threadIdx.x >> 6;
    int s = blockIdx.y * 4 + wave;
    const float4* h4 = (const float4*)(h + ((size_t)b * T + s) * D);
    const float4* w4 = (const float4*)ws;
    float acc = 0.f;
    for (int k = lane; k < D / 4; k += 64) {  // 2 iters
        float4 a = h4[k], w = w4[k];
        acc += a.x * w.x + a.y * w.y + a.z * w.z + a.w * w.w;
    }
    for (int off = 32; off; off >>= 1) acc += __shfl_down(acc, off);
    if (lane == 0) sc[b * T + s] = acc + cvec[b];
}

// ---------------------------------------------------------------------------
// Kernel C: per batch — exact top-1024 via 4-pass 8-bit radix select on ord keys,
// ties broken by smallest index; emit normalized (idx, weight) list.
__global__ __launch_bounds__(1024) void k_select(const float* __restrict__ sc,
                                                 unsigned* __restrict__ selI,
                                                 float* __restrict__ selW) {
    int b = blockIdx.x;
    int tid = threadIdx.x;
    __shared__ unsigned ordk[T];     // 16KB
    __shared__ int hist[256];        // 1KB
    __shared__ float red[16];
    __shared__ unsigned sI[KKEEP];   // 4KB
    __shared__ float sW[KKEEP];      // 4KB
    __shared__ unsigned tieI[T];     // 16KB (worst case)
    __shared__ unsigned sh_pv;
    __shared__ int sh_r, sh_cnt, sh_tiecnt;
    __shared__ float sh_max, sh_inv;

    float sv[4];
    float lmax = -INFINITY;
#pragma unroll
    for (int k = 0; k < 4; ++k) {
        int i = tid + k * 1024;
        float v = sc[b * T + i];
        sv[k] = v;
        ordk[i] = f2ord(v);
        lmax = fmaxf(lmax, v);
    }
    for (int off = 32; off; off >>= 1) lmax = fmaxf(lmax, __shfl_down(lmax, off));
    if ((tid & 63) == 0) red[tid >> 6] = lmax;
    __syncthreads();
    if (tid == 0) {
        float m = red[0];
        for (int w = 1; w < 16; ++w) m = fmaxf(m, red[w]);
        sh_max = m; sh_pv = 0; sh_r = KKEEP; sh_cnt = 0; sh_tiecnt = 0;
    }
    __syncthreads();

    for (int p = 24; p >= 0; p -= 8) {
        if (tid < 256) hist[tid] = 0;
        __syncthreads();
        unsigned pv = sh_pv;
#pragma unroll
        for (int k = 0; k < 4; ++k) {
            unsigned key = ordk[tid + k * 1024];
            bool act = (p == 24) || ((key >> (p + 8)) == pv);
            if (act) atomicAdd(&hist[(key >> p) & 255], 1);
        }
        __syncthreads();
        if (tid < 64) {  // wave 0: suffix-scan 256 bins, locate rank r
            int r = sh_r;
            int c0 = hist[tid * 4], c1 = hist[tid * 4 + 1];
            int c2 = hist[tid * 4 + 2], c3 = hist[tid * 4 + 3];
            int s = c0 + c1 + c2 + c3;
            int cum = s;
            for (int off = 1; off < 64; off <<= 1) {
                int v = __shfl_down(cum, off);
                if (tid + off < 64) cum += v;
            }
            int base = cum - s;
            if (base < r && r <= cum) {  // exactly one lane
                int d, sg;
                if (r <= base + c3)                { d = 3; sg = base; }
                else if (r <= base + c3 + c2)      { d = 2; sg = base + c3; }
                else if (r <= base + c3 + c2 + c1) { d = 1; sg = base + c3 + c2; }
                else                               { d = 0; sg = base + c3 + c2 + c1; }
                sh_pv = (pv << 8) | (unsigned)(tid * 4 + d);
                sh_r = r - sg;
            }
        }
        __syncthreads();
    }

    unsigned vstar = sh_pv;
    int rtie = sh_r;
    float gmax = sh_max;

#pragma unroll
    for (int k = 0; k < 4; ++k) {
        int i = tid + k * 1024;
        unsigned key = ordk[i];
        if (key > vstar) {
            int pos = atomicAdd(&sh_cnt, 1);
            sI[pos] = (unsigned)i;
            sW[pos] = __expf(sv[k] - gmax);
        } else if (key == vstar) {
            int pos = atomicAdd(&sh_tiecnt, 1);
            tieI[pos] = (unsigned)i;
        }
    }
    __syncthreads();

    int tcnt = sh_tiecnt;
    float tw = __expf(ord2f(vstar) - gmax);
    for (int t = tid; t < tcnt; t += 1024) {
        unsigned my = tieI[t];
        int rank = 0;
        for (int o = 0; o < tcnt; ++o) rank += (tieI[o] < my);
        if (rank < rtie) {
            int pos = atomicAdd(&sh_cnt, 1);
            sI[pos] = my;
            sW[pos] = tw;
        }
    }
    __syncthreads();

    float lsum = sW[tid];
    for (int off = 32; off; off >>= 1) lsum += __shfl_down(lsum, off);
    if ((tid & 63) == 0) red[tid >> 6] = lsum;
    __syncthreads();
    if (tid == 0) {
        float s = 0.f;
        for (int w = 0; w < 16; ++w) s += red[w];
        sh_inv = 1.0f / s;
    }
    __syncthreads();
    selI[b * KKEEP + tid] = sI[tid];
    selW[b * KKEEP + tid] = sW[tid] * sh_inv;
}

// ---------------------------------------------------------------------------
// Kernel D: part[b,y,:] = sum over 32 selected rows of w * h[b,idx,:]
// grid (B, 32), block 512 = 4 groups x 128; no atomics — partials to workspace.
__global__ __launch_bounds__(512) void k_wsum(const float* __restrict__ h,
                                              const unsigned* __restrict__ selI,
                                              const float* __restrict__ selW,
                                              float* __restrict__ part) {
    int b = blockIdx.x, y = blockIdx.y, tid = threadIdx.x;
    int g = tid >> 7, l = tid & 127;
    int e0 = y * 32;
    __shared__ float4 red4[512];
    float4 acc = make_float4(0.f, 0.f, 0.f, 0.f);
    for (int e = g; e < 32; e += 4) {
        unsigned s = selI[b * KKEEP + e0 + e];
        float w = selW[b * KKEEP + e0 + e];
        float4 v = ((const float4*)(h + ((size_t)b * T + s) * D))[l];
        acc.x += w * v.x; acc.y += w * v.y; acc.z += w * v.z; acc.w += w * v.w;
    }
    red4[tid] = acc;
    __syncthreads();
    if (tid < 128) {
        float4 a = red4[tid], b4 = red4[tid + 128], c = red4[tid + 256], d4 = red4[tid + 384];
        float4 r = make_float4(a.x + b4.x + c.x + d4.x, a.y + b4.y + c.y + d4.y,
                               a.z + b4.z + c.z + d4.z, a.w + b4.w + c.w + d4.w);
        ((float4*)part)[(b * 32 + y) * 128 + tid] = r;
    }
}

// ---------------------------------------------------------------------------
// Kernel E: reduce 32 partials in LDS, then out[b,j] = wsum . Wv[:,j] + bv[j]
__global__ void k_out(const float* __restrict__ part, const float* __restrict__ Wv,
                      const float* __restrict__ bv, float* __restrict__ out) {
    int b = blockIdx.x, tid = threadIdx.x;
    int j = blockIdx.y * 256 + tid;
    __shared__ float ws_[D];
    for (int d = tid; d < D; d += 256) {
        float s = 0.f;
#pragma unroll 8
        for (int p = 0; p < 32; ++p) s += part[(size_t)(b * 32 + p) * D + d];
        ws_[d] = s;
    }
    __syncthreads();
    float acc = bv[j];
#pragma unroll 4
    for (int d = 0; d < D; ++d) acc += ws_[d] * Wv[(size_t)d * D + j];
    out[b * D + j] = acc;
}

// ---------------------------------------------------------------------------
extern "C" void kernel_launch(void* const* d_in, const int* in_sizes, int n_in,
                              void* d_out, int out_size, void* d_ws, size_t ws_size,
                              hipStream_t stream) {
    const float* h  = (const float*)d_in[0];
    const float* Wq = (const float*)d_in[1];
    const float* bq = (const float*)d_in[2];
    const float* Wk = (const float*)d_in[3];
    const float* bk = (const float*)d_in[4];
    const float* Wv = (const float*)d_in[5];
    const float* bv = (const float*)d_in[6];
    float* out = (float*)d_out;

    float* ws = (float*)d_ws;
    float* wvec    = ws;                       // B*D   = 2048
    float* cvec    = ws + 2048;                // B (padded to 256)
    float* sc      = ws + 2304;                // B*T   = 16384
    unsigned* selI = (unsigned*)(ws + 18688);  // B*KKEEP = 4096
    float* selW    = ws + 22784;               // B*KKEEP = 4096
    float* part    = ws + 26880;               // B*32*D = 65536

    k_prep<<<dim3(B), 1024, 0, stream>>>(h, Wq, bq, Wk, bk, wvec, cvec);
    k_scores<<<dim3(B, T / 4), 256, 0, stream>>>(h, wvec, cvec, sc);
    k_select<<<dim3(B), 1024, 0, stream>>>(sc, selI, selW);
    k_wsum<<<dim3(B, 32), 512, 0, stream>>>(h, selI, selW, part);
    k_out<<<dim3(B, 2), 256, 0, stream>>>(part, Wv, bv, out);
}